// Round 3
// baseline (98.980 us; speedup 1.0000x reference)
//
#include <hip/hip_runtime.h>
#include <hip/hip_fp16.h>
#include <stdint.h>

#define W_ 512
#define H_ 512
#define HW_ (512 * 512)

#define SCAN_B 256
#define SCAN_I 8
#define SCAN_TILE (SCAN_B * SCAN_I)   // 2048
#define SCAN_SHIFT 11                 // log2(SCAN_TILE)
#define RMAX 8

// ---- projection: exact replica of the reference f32 arithmetic ----
__device__ __forceinline__ int project_pix(float x, float y, float z) {
    float zz = z + 1e-6f;
    float xf = x / zz * 512.0f + 256.0f;
    float yf = y / zz * 512.0f + 256.0f;
    xf = fminf(fmaxf(xf, -1e9f), 1e9f);
    yf = fminf(fmaxf(yf, -1e9f), 1e9f);
    int xi = (int)xf;   // trunc toward zero
    int yi = (int)yf;
    if (xi >= 0 && xi < W_ && yi >= 0 && yi < H_) return yi * W_ + xi;
    return -1;
}

// ---- fast zero-init (replaces 39us runtime fill) ----
__global__ void __launch_bounds__(256) k_init(uint4* __restrict__ p, int n4) {
    int i = blockIdx.x * blockDim.x + threadIdx.x;
    if (i < n4) p[i] = make_uint4(0u, 0u, 0u, 0u);
}

// ---- pass 1: per-pixel counts, 4 gaussians/thread via float4 loads ----
__global__ void __launch_bounds__(256) k_count(const float4* __restrict__ xyz4,
                                               unsigned int* __restrict__ cnt,
                                               int N, int total4) {
    int t = blockIdx.x * blockDim.x + threadIdx.x;
    if (t >= total4) return;
    float4 v0 = xyz4[3 * (size_t)t + 0];
    float4 v1 = xyz4[3 * (size_t)t + 1];
    float4 v2 = xyz4[3 * (size_t)t + 2];
    float xs[4] = {v0.x, v0.w, v1.z, v2.y};
    float ys[4] = {v0.y, v1.x, v1.w, v2.z};
    float zs[4] = {v0.z, v1.y, v2.x, v2.w};
    int g0 = 4 * t;
#pragma unroll
    for (int j = 0; j < 4; ++j) {
        int pix = project_pix(xs[j], ys[j], zs[j]);
        if (pix >= 0) {
            int b = (g0 + j) / N;
            atomicAdd(&cnt[(size_t)b * HW_ + pix], 1u);
        }
    }
}

// ---- scan A: per-2048-tile exclusive scan; per-tile totals to sums ----
__global__ void __launch_bounds__(SCAN_B) k_scanA(const unsigned int* __restrict__ cnt,
                                                  unsigned int* __restrict__ off,
                                                  unsigned int* __restrict__ sums, int n) {
    __shared__ unsigned int sm[SCAN_B];
    int base = blockIdx.x * SCAN_TILE + threadIdx.x * SCAN_I;
    unsigned int it[SCAN_I];
    unsigned int tot = 0;
#pragma unroll
    for (int i = 0; i < SCAN_I; ++i) {
        int ix = base + i;
        it[i] = (ix < n) ? cnt[ix] : 0u;
        tot += it[i];
    }
    sm[threadIdx.x] = tot;
    __syncthreads();
    for (int d = 1; d < SCAN_B; d <<= 1) {
        unsigned int v = (threadIdx.x >= (unsigned)d) ? sm[threadIdx.x - d] : 0u;
        __syncthreads();
        sm[threadIdx.x] += v;
        __syncthreads();
    }
    unsigned int incl = sm[threadIdx.x];
    unsigned int excl = incl - tot;
    if (threadIdx.x == SCAN_B - 1) sums[blockIdx.x] = incl;
    unsigned int run = excl;
#pragma unroll
    for (int i = 0; i < SCAN_I; ++i) {
        int ix = base + i;
        if (ix < n) off[ix] = run;
        run += it[i];
    }
}

// ---- scan B: exclusive scan of the (<=1024) tile totals, in place ----
__global__ void __launch_bounds__(1024) k_scanB(unsigned int* __restrict__ sums, int n) {
    __shared__ unsigned int sm[1024];
    int t = threadIdx.x;
    unsigned int v = (t < n) ? sums[t] : 0u;
    sm[t] = v;
    __syncthreads();
    for (int d = 1; d < 1024; d <<= 1) {
        unsigned int u = (t >= d) ? sm[t - d] : 0u;
        __syncthreads();
        sm[t] += u;
        __syncthreads();
    }
    if (t < n) sums[t] = sm[t] - v;  // exclusive
}

// ---- pass 2: scatter fat records; off[p] becomes end-cursor ----
// record: .x = z bits, .y = idx within batch, .z = f16(o)|f16(r)<<16, .w = f16(g)|f16(b)<<16
__global__ void __launch_bounds__(256) k_scatter(const float4* __restrict__ xyz4,
                                                 const float4* __restrict__ op4,
                                                 const float4* __restrict__ col4,
                                                 unsigned int* __restrict__ off,
                                                 const unsigned int* __restrict__ sums,
                                                 uint4* __restrict__ bins,
                                                 int N, int total4) {
    int t = blockIdx.x * blockDim.x + threadIdx.x;
    if (t >= total4) return;
    float4 v0 = xyz4[3 * (size_t)t + 0];
    float4 v1 = xyz4[3 * (size_t)t + 1];
    float4 v2 = xyz4[3 * (size_t)t + 2];
    float4 o4 = op4[t];
    float4 c0 = col4[3 * (size_t)t + 0];
    float4 c1 = col4[3 * (size_t)t + 1];
    float4 c2 = col4[3 * (size_t)t + 2];
    float xs[4] = {v0.x, v0.w, v1.z, v2.y};
    float ys[4] = {v0.y, v1.x, v1.w, v2.z};
    float zs[4] = {v0.z, v1.y, v2.x, v2.w};
    float os[4] = {o4.x, o4.y, o4.z, o4.w};
    float cr[4] = {c0.x, c0.w, c1.z, c2.y};
    float cg[4] = {c0.y, c1.x, c1.w, c2.z};
    float cb[4] = {c0.z, c1.y, c2.x, c2.w};
    int g0 = 4 * t;
#pragma unroll
    for (int j = 0; j < 4; ++j) {
        int pix = project_pix(xs[j], ys[j], zs[j]);
        if (pix >= 0) {
            int g = g0 + j;
            int b = g / N;
            size_t p = (size_t)b * HW_ + pix;
            unsigned int old = atomicAdd(&off[p], 1u);
            unsigned int pos = old + sums[p >> SCAN_SHIFT];
            uint4 rec;
            rec.x = __float_as_uint(zs[j]);
            rec.y = (unsigned int)(g - b * N);
            rec.z = (unsigned int)__half_as_ushort(__float2half_rn(os[j])) |
                    ((unsigned int)__half_as_ushort(__float2half_rn(cr[j])) << 16);
            rec.w = (unsigned int)__half_as_ushort(__float2half_rn(cg[j])) |
                    ((unsigned int)__half_as_ushort(__float2half_rn(cb[j])) << 16);
            bins[pos] = rec;
        }
    }
}

__device__ __forceinline__ float lo_h(unsigned int u) {
    return __half2float(__ushort_as_half((unsigned short)(u & 0xffffu)));
}
__device__ __forceinline__ float hi_h(unsigned int u) {
    return __half2float(__ushort_as_half((unsigned short)(u >> 16)));
}

// ---- pass 3: streaming per-pixel ordered composite ----
__global__ void __launch_bounds__(256) k_composite(const unsigned int* __restrict__ cnt,
                                                   const unsigned int* __restrict__ off,
                                                   const unsigned int* __restrict__ sums,
                                                   const uint4* __restrict__ bins,
                                                   float* __restrict__ out, int B) {
    int p = blockIdx.x * blockDim.x + threadIdx.x;
    int nb = B * HW_;
    if (p >= nb) return;
    int bt = p / HW_;
    int pl = p - bt * HW_;

    int k = (int)cnt[p];
    float r = 0.f, g2 = 0.f, bl = 0.f, depth = 0.f, T = 1.f;

    if (k > 0) {
        // off[p] was bumped to end by scatter; add tile base, subtract k
        int base = (int)(off[p] + sums[p >> SCAN_SHIFT]) - k;

        if (k <= RMAX) {
            float z_[RMAX];
            int   i_[RMAX];
            unsigned int pa_[RMAX], pb_[RMAX];
#pragma unroll
            for (int t = 0; t < RMAX; ++t) {
                if (t < k) {
                    uint4 rec = bins[base + t];
                    z_[t] = __uint_as_float(rec.x);
                    i_[t] = (int)rec.y;
                    pa_[t] = rec.z;
                    pb_[t] = rec.w;
                } else {
                    z_[t] = -__builtin_inff();
                    i_[t] = 0x7fffffff;
                    pa_[t] = 0u;
                    pb_[t] = 0u;
                }
            }
            // sort desc by z, ties asc by idx — Batcher 8-network, 19 CEs,
            // all indices static => stays in registers
#define CE(I, J)                                                              \
            {                                                                 \
                bool sw = (z_[J] > z_[I]) || (z_[J] == z_[I] && i_[J] < i_[I]); \
                if (sw) {                                                     \
                    float tz = z_[I]; z_[I] = z_[J]; z_[J] = tz;              \
                    int ti = i_[I]; i_[I] = i_[J]; i_[J] = ti;                \
                    unsigned int ta = pa_[I]; pa_[I] = pa_[J]; pa_[J] = ta;   \
                    unsigned int tb = pb_[I]; pb_[I] = pb_[J]; pb_[J] = tb;   \
                }                                                             \
            }
            CE(0,1) CE(2,3) CE(4,5) CE(6,7)
            CE(0,2) CE(1,3) CE(4,6) CE(5,7)
            CE(1,2) CE(5,6)
            CE(0,4) CE(1,5) CE(2,6) CE(3,7)
            CE(2,4) CE(3,5)
            CE(1,2) CE(3,4) CE(5,6)
#undef CE
#pragma unroll
            for (int t = 0; t < RMAX; ++t) {
                if (t < k) {
                    float o  = lo_h(pa_[t]);
                    float cr = hi_h(pa_[t]);
                    float cg = lo_h(pb_[t]);
                    float cb = hi_h(pb_[t]);
                    float a = o * T;
                    r  += a * cr;
                    g2 += a * cg;
                    bl += a * cb;
                    T *= (1.0f - o);
                    depth = z_[t];   // last valid = min z = front-most
                }
            }
        } else {
            // exact fallback for k > RMAX (essentially never): O(k^2) selection
            float prev_z = __builtin_inff();
            int prev_i = -1;
            for (int s = 0; s < k; ++s) {
                float best_z = -__builtin_inff();
                int best_i = 0x7fffffff;
                unsigned int ba = 0u, bb = 0u;
                for (int t2 = 0; t2 < k; ++t2) {
                    uint4 rec = bins[base + t2];
                    float z = __uint_as_float(rec.x);
                    int   i = (int)rec.y;
                    bool after  = (z < prev_z) || (z == prev_z && i > prev_i);
                    bool better = (z > best_z) || (z == best_z && i < best_i);
                    if (after && better) { best_z = z; best_i = i; ba = rec.z; bb = rec.w; }
                }
                float o  = lo_h(ba);
                float cr = hi_h(ba);
                float cg = lo_h(bb);
                float cb = hi_h(bb);
                float a = o * T;
                r  += a * cr;
                g2 += a * cg;
                bl += a * cb;
                T *= (1.0f - o);
                depth = best_z;
                prev_z = best_z;
                prev_i = best_i;
            }
        }
    }

    size_t HWs = (size_t)HW_;
    out[((size_t)bt * 3 + 0) * HWs + pl] = r;
    out[((size_t)bt * 3 + 1) * HWs + pl] = g2;
    out[((size_t)bt * 3 + 2) * HWs + pl] = bl;
    out[(size_t)B * 3 * HWs + (size_t)bt * HWs + pl] = depth;
}

extern "C" void kernel_launch(void* const* d_in, const int* in_sizes, int n_in,
                              void* d_out, int out_size, void* d_ws, size_t ws_size,
                              hipStream_t stream) {
    const float* xyz     = (const float*)d_in[0];
    // d_in[1] = scale (unused), d_in[2] = rotation (unused)
    const float* opacity = (const float*)d_in[3];
    const float* color   = (const float*)d_in[4];
    float* out = (float*)d_out;

    int B = out_size / (4 * HW_);        // render (B,3,H,W) + depth (B,1,H,W)
    int N = in_sizes[0] / (3 * B);
    int total = B * N;
    int nb = B * HW_;
    int nblocks = (nb + SCAN_TILE - 1) / SCAN_TILE;   // 1024 for B=8

    unsigned int* cnt  = (unsigned int*)d_ws;          // nb
    unsigned int* off  = cnt + nb;                     // nb
    unsigned int* sums = off + nb;                     // nblocks (<=1024)
    uint4*        bins = (uint4*)(sums + 1024);        // total records (16B each)

    int blk = 256;
    int n4 = nb / 4;
    k_init<<<(n4 + blk - 1) / blk, blk, 0, stream>>>((uint4*)cnt, n4);

    int total4 = total / 4;
    k_count<<<(total4 + blk - 1) / blk, blk, 0, stream>>>((const float4*)xyz, cnt, N, total4);

    k_scanA<<<nblocks, SCAN_B, 0, stream>>>(cnt, off, sums, nb);
    k_scanB<<<1, 1024, 0, stream>>>(sums, nblocks);

    k_scatter<<<(total4 + blk - 1) / blk, blk, 0, stream>>>((const float4*)xyz,
                                                            (const float4*)opacity,
                                                            (const float4*)color,
                                                            off, sums, bins, N, total4);

    k_composite<<<(nb + blk - 1) / blk, blk, 0, stream>>>(cnt, off, sums, bins, out, B);
}

// Round 4
// 44.780 us; speedup vs baseline: 2.2103x; 2.2103x over previous
//
#include <hip/hip_runtime.h>
#include <hip/hip_fp16.h>
#include <stdint.h>

#define W_ 512
#define H_ 512
#define HW_ (512 * 512)
#define RMAX 6          // per-pixel slot capacity (P(k>6) ~ 1e-9 per pixel)
#define OVF_CAP 65536   // overflow list capacity (correctness net, ~never used)

// ---- projection: exact replica of the reference f32 arithmetic ----
__device__ __forceinline__ int project_pix(float x, float y, float z) {
    float zz = z + 1e-6f;
    float xf = x / zz * 512.0f + 256.0f;
    float yf = y / zz * 512.0f + 256.0f;
    xf = fminf(fmaxf(xf, -1e9f), 1e9f);
    yf = fminf(fmaxf(yf, -1e9f), 1e9f);
    int xi = (int)xf;   // trunc toward zero
    int yi = (int)yf;
    if (xi >= 0 && xi < W_ && yi >= 0 && yi < H_) return yi * W_ + xi;
    return -1;
}

__device__ __forceinline__ float lo_h(unsigned int u) {
    return __half2float(__ushort_as_half((unsigned short)(u & 0xffffu)));
}
__device__ __forceinline__ float hi_h(unsigned int u) {
    return __half2float(__ushort_as_half((unsigned short)(u >> 16)));
}

// ---- pass 0: zero cnt + overflow header ----
__global__ void __launch_bounds__(256) k_init(uint4* __restrict__ p, int n4) {
    int i = blockIdx.x * blockDim.x + threadIdx.x;
    if (i < n4) p[i] = make_uint4(0u, 0u, 0u, 0u);
}

// ---- pass 1: single-pass build of per-pixel slot arrays ----
// record: .x = z bits, .y = global idx, .z = f16(o)|f16(r)<<16, .w = f16(g)|f16(b)<<16
__global__ void __launch_bounds__(256) k_build(const float4* __restrict__ xyz4,
                                               const float4* __restrict__ op4,
                                               const float4* __restrict__ col4,
                                               unsigned int* __restrict__ cnt,
                                               uint4* __restrict__ slots,
                                               unsigned int* __restrict__ ovf_hdr,
                                               unsigned int* __restrict__ ovf_pix,
                                               uint4* __restrict__ ovf_rec,
                                               int N, int total4) {
    int t = blockIdx.x * blockDim.x + threadIdx.x;
    if (t >= total4) return;
    float4 v0 = xyz4[3 * (size_t)t + 0];
    float4 v1 = xyz4[3 * (size_t)t + 1];
    float4 v2 = xyz4[3 * (size_t)t + 2];
    float4 o4 = op4[t];
    float4 c0 = col4[3 * (size_t)t + 0];
    float4 c1 = col4[3 * (size_t)t + 1];
    float4 c2 = col4[3 * (size_t)t + 2];
    float xs[4] = {v0.x, v0.w, v1.z, v2.y};
    float ys[4] = {v0.y, v1.x, v1.w, v2.z};
    float zs[4] = {v0.z, v1.y, v2.x, v2.w};
    float os[4] = {o4.x, o4.y, o4.z, o4.w};
    float cr[4] = {c0.x, c0.w, c1.z, c2.y};
    float cg[4] = {c0.y, c1.x, c1.w, c2.z};
    float cb[4] = {c0.z, c1.y, c2.x, c2.w};
    int g0 = 4 * t;
    size_t pbase = (size_t)(g0 / N) * HW_;   // 4 consecutive g share a batch (N%4==0)
#pragma unroll
    for (int j = 0; j < 4; ++j) {
        int pix = project_pix(xs[j], ys[j], zs[j]);
        if (pix >= 0) {
            size_t p = pbase + pix;
            unsigned int s = atomicAdd(&cnt[p], 1u);
            uint4 rec;
            rec.x = __float_as_uint(zs[j]);
            rec.y = (unsigned int)(g0 + j);
            rec.z = (unsigned int)__half_as_ushort(__float2half_rn(os[j])) |
                    ((unsigned int)__half_as_ushort(__float2half_rn(cr[j])) << 16);
            rec.w = (unsigned int)__half_as_ushort(__float2half_rn(cg[j])) |
                    ((unsigned int)__half_as_ushort(__float2half_rn(cb[j])) << 16);
            if (s < RMAX) {
                slots[p * RMAX + s] = rec;
            } else {
                unsigned int i = atomicAdd(ovf_hdr, 1u);
                if (i < OVF_CAP) { ovf_pix[i] = (unsigned int)p; ovf_rec[i] = rec; }
            }
        }
    }
}

// ---- pass 2: streaming composite, 4 pixels per thread ----
__global__ void __launch_bounds__(256) k_composite(const unsigned int* __restrict__ cnt,
                                                   const uint4* __restrict__ slots,
                                                   const unsigned int* __restrict__ ovf_hdr,
                                                   const unsigned int* __restrict__ ovf_pix,
                                                   const uint4* __restrict__ ovf_rec,
                                                   float* __restrict__ out, int B) {
    int q = blockIdx.x * blockDim.x + threadIdx.x;
    int nb4 = B * (HW_ / 4);
    if (q >= nb4) return;
    int p0 = 4 * q;
    int b = p0 / HW_;            // compile-time divisor; 4 pixels share a batch
    int pl = p0 - b * HW_;

    uint4 c4 = ((const uint4*)cnt)[q];
    unsigned int ks[4] = {c4.x, c4.y, c4.z, c4.w};
    float r4[4], g4[4], b4[4], d4[4];

#pragma unroll
    for (int j = 0; j < 4; ++j) {
        int k = (int)ks[j];
        float r = 0.f, g2 = 0.f, bl = 0.f, depth = 0.f, T = 1.f;
        if (k > 0) {
            size_t sbase = (size_t)(p0 + j) * RMAX;
            if (k <= RMAX) {
                float z_[8];
                int   i_[8];
                unsigned int pa_[8], pb_[8];
#pragma unroll
                for (int t = 0; t < 8; ++t) {
                    if (t < RMAX && t < k) {
                        uint4 rec = slots[sbase + t];
                        z_[t] = __uint_as_float(rec.x);
                        i_[t] = (int)rec.y;
                        pa_[t] = rec.z;
                        pb_[t] = rec.w;
                    } else {
                        z_[t] = -__builtin_inff();
                        i_[t] = 0x7fffffff;
                        pa_[t] = 0u;
                        pb_[t] = 0u;
                    }
                }
                // sort desc by z, ties asc by idx — Batcher 8-network (19 CEs),
                // static indices => registers only
#define CE(I, J)                                                                  \
                {                                                                 \
                    bool sw = (z_[J] > z_[I]) || (z_[J] == z_[I] && i_[J] < i_[I]); \
                    if (sw) {                                                     \
                        float tz = z_[I]; z_[I] = z_[J]; z_[J] = tz;              \
                        int ti = i_[I]; i_[I] = i_[J]; i_[J] = ti;                \
                        unsigned int ta = pa_[I]; pa_[I] = pa_[J]; pa_[J] = ta;   \
                        unsigned int tb = pb_[I]; pb_[I] = pb_[J]; pb_[J] = tb;   \
                    }                                                             \
                }
                CE(0,1) CE(2,3) CE(4,5) CE(6,7)
                CE(0,2) CE(1,3) CE(4,6) CE(5,7)
                CE(1,2) CE(5,6)
                CE(0,4) CE(1,5) CE(2,6) CE(3,7)
                CE(2,4) CE(3,5)
                CE(1,2) CE(3,4) CE(5,6)
#undef CE
#pragma unroll
                for (int t = 0; t < RMAX; ++t) {
                    if (t < k) {
                        float o  = lo_h(pa_[t]);
                        float rr = hi_h(pa_[t]);
                        float gg = lo_h(pb_[t]);
                        float bb = hi_h(pb_[t]);
                        float a = o * T;
                        r  += a * rr;
                        g2 += a * gg;
                        bl += a * bb;
                        T *= (1.0f - o);
                        depth = z_[t];   // last valid = min z = front-most
                    }
                }
            } else {
                // cold exact path (k > RMAX, ~never): selection over slots + overflow
                unsigned int nov = ovf_hdr[0];
                if (nov > OVF_CAP) nov = OVF_CAP;
                unsigned int ptag = (unsigned int)(p0 + j);
                float prev_z = __builtin_inff();
                int prev_i = -1;
                for (int s = 0; s < k; ++s) {
                    float best_z = -__builtin_inff();
                    int best_i = 0x7fffffff;
                    unsigned int ba = 0u, bb2 = 0u;
                    for (int t2 = 0; t2 < RMAX; ++t2) {
                        uint4 rec = slots[sbase + t2];
                        float z = __uint_as_float(rec.x);
                        int   i = (int)rec.y;
                        bool after  = (z < prev_z) || (z == prev_z && i > prev_i);
                        bool better = (z > best_z) || (z == best_z && i < best_i);
                        if (after && better) { best_z = z; best_i = i; ba = rec.z; bb2 = rec.w; }
                    }
                    for (unsigned int t2 = 0; t2 < nov; ++t2) {
                        if (ovf_pix[t2] == ptag) {
                            uint4 rec = ovf_rec[t2];
                            float z = __uint_as_float(rec.x);
                            int   i = (int)rec.y;
                            bool after  = (z < prev_z) || (z == prev_z && i > prev_i);
                            bool better = (z > best_z) || (z == best_z && i < best_i);
                            if (after && better) { best_z = z; best_i = i; ba = rec.z; bb2 = rec.w; }
                        }
                    }
                    float o  = lo_h(ba);
                    float rr = hi_h(ba);
                    float gg = lo_h(bb2);
                    float bb = hi_h(bb2);
                    float a = o * T;
                    r  += a * rr;
                    g2 += a * gg;
                    bl += a * bb;
                    T *= (1.0f - o);
                    depth = best_z;
                    prev_z = best_z;
                    prev_i = best_i;
                }
            }
        }
        r4[j] = r; g4[j] = g2; b4[j] = bl; d4[j] = depth;
    }

    size_t HWs = (size_t)HW_;
    *(float4*)(out + ((size_t)b * 3 + 0) * HWs + pl) = make_float4(r4[0], r4[1], r4[2], r4[3]);
    *(float4*)(out + ((size_t)b * 3 + 1) * HWs + pl) = make_float4(g4[0], g4[1], g4[2], g4[3]);
    *(float4*)(out + ((size_t)b * 3 + 2) * HWs + pl) = make_float4(b4[0], b4[1], b4[2], b4[3]);
    *(float4*)(out + (size_t)B * 3 * HWs + (size_t)b * HWs + pl) =
        make_float4(d4[0], d4[1], d4[2], d4[3]);
}

extern "C" void kernel_launch(void* const* d_in, const int* in_sizes, int n_in,
                              void* d_out, int out_size, void* d_ws, size_t ws_size,
                              hipStream_t stream) {
    const float* xyz     = (const float*)d_in[0];
    // d_in[1] = scale (unused), d_in[2] = rotation (unused)
    const float* opacity = (const float*)d_in[3];
    const float* color   = (const float*)d_in[4];
    float* out = (float*)d_out;

    int B = out_size / (4 * HW_);        // render (B,3,H,W) + depth (B,1,H,W)
    int N = in_sizes[0] / (3 * B);
    int total = B * N;
    int nb = B * HW_;

    // ws layout (u32 units): [cnt: nb][ovf_hdr: 1024][ovf_pix: OVF_CAP]
    //                        [ovf_rec: OVF_CAP uint4][slots: nb*RMAX uint4]
    unsigned int* cnt     = (unsigned int*)d_ws;
    unsigned int* ovf_hdr = cnt + nb;
    unsigned int* ovf_pix = ovf_hdr + 1024;
    uint4*        ovf_rec = (uint4*)(ovf_pix + OVF_CAP);
    uint4*        slots   = ovf_rec + OVF_CAP;
    // total: 8MB + 4KB + 0.25MB + 1MB + 201MB ≈ 210MB < 256MiB ws

    int blk = 256;
    int zw4 = (nb + 1024) / 4;           // zero cnt + ovf_hdr
    k_init<<<(zw4 + blk - 1) / blk, blk, 0, stream>>>((uint4*)cnt, zw4);

    int total4 = total / 4;
    k_build<<<(total4 + blk - 1) / blk, blk, 0, stream>>>((const float4*)xyz,
                                                          (const float4*)opacity,
                                                          (const float4*)color,
                                                          cnt, slots, ovf_hdr, ovf_pix, ovf_rec,
                                                          N, total4);

    int nb4 = nb / 4;
    k_composite<<<(nb4 + blk - 1) / blk, blk, 0, stream>>>(cnt, slots, ovf_hdr, ovf_pix, ovf_rec,
                                                           out, B);
}